// Round 18
// baseline (238.236 us; speedup 1.0000x reference)
//
#include <hip/hip_runtime.h>
#include <hip/hip_fp16.h>

// MultiHeadAttention_64106681860559 — round 18: R12 base (best measured) +
// softmax ELIMINATED: S-GEMM epilogue emits block-local row stats (m_b, l_b),
// a tiny combine kernel produces global (m*, 1/l*), and the final GEMM applies
// p = exp2(s*log2e - m*)*invl to A-fragments in-register. P buffer dies.
//
// Workspace (~112 MB):
//   xb fp16 [4096][1024] @0 | wqkvT fp16 [3072][1024] @8M | qkv fp16 [4096][3072] @14M
//   S fp16 [4096][4096] @46M | partials f32x2 [4096][16] @78M | mstar @79M |
//   linv @79M+64K | vwT fp16 [1024][4096] @118M | woutT @126M |
//   parts fp16 4x[4096][1024] @14M (qkv dead by final GEMM)

typedef _Float16 half_t;
typedef _Float16 half8 __attribute__((ext_vector_type(8)));
typedef _Float16 half4 __attribute__((ext_vector_type(4)));
typedef float f32x4 __attribute__((ext_vector_type(4)));

static constexpr int N_TOK = 4096;
static constexpr int LATENT = 1024;
static constexpr int QKVN = 3072;
static constexpr float LOG2E = 1.44269504f;

#define DEVI __device__ __forceinline__
#define BAR() __builtin_amdgcn_s_barrier()
#define PRIO(x) __builtin_amdgcn_s_setprio(x)
#define VMCNT(n) asm volatile("s_waitcnt vmcnt(" #n ")" ::: "memory")

DEVI void gld_lds16(const half_t* g, half_t* l) {
  __builtin_amdgcn_global_load_lds(
      (const __attribute__((address_space(1))) void*)g,
      (__attribute__((address_space(3))) void*)l,
      16, 0, 0);
}

DEVI f32x4 MFMA(half8 a, half8 b, f32x4 c) {
  return __builtin_amdgcn_mfma_f32_16x16x32_f16(a, b, c, 0, 0, 0);
}

// ---- 64B-row swizzle (0 conflicts, R3/R9/R12-proven): phys 16B slot p of row
// r holds logical slot p ^ ((r>>1)&3). Pre-swizzled source; XOR on read.

// Stage a [256][32] fp16 half-K-tile (1024 x 16B chunks, 512 thr, 2 each).
DEVI void stageH(const half_t* __restrict__ g, int ld, half_t* lbase, int tid) {
#pragma unroll
  for (int i = 0; i < 2; ++i) {
    int c = tid + i * 512;
    int r = c >> 2;
    int k8 = ((c & 3) ^ ((r >> 1) & 3)) * 8;
    gld_lds16(g + (size_t)r * ld + k8, lbase + c * 8);
  }
}

// ---------------------------------------------------------------------------
// 256x256 GEMM (R12 schedule): 512 thr = 8 waves (2Mx4N), per-wave 128x64.
// BK=64 as two 32-wide K-halves; 2 phases/K-tile:
//  {12 ds_reads | stage A+B next-tile-same-half | BAR | prio1 | 32 MFMA |
//   prio0 | vmcnt(4) | BAR}
// MODE 0: +bias, cols<1024 * 0.125, fp16 out (qkv)
// MODE 1: fp16 out (S) + block-local softmax stats -> partials[4096][16]
// MODE 2: A=S with on-the-fly p=exp2(s*log2e-mstar)*linv; fp16 z-sliced partials
// ---------------------------------------------------------------------------
template <int MODE>
__launch_bounds__(512, 2)
__global__ void gemm8h(const half_t* __restrict__ A, int lda,
                       const half_t* __restrict__ B, int ldb,
                       void* __restrict__ Cout, int ldc,
                       const float* __restrict__ bias, int K,
                       float2* __restrict__ partials,
                       const float* __restrict__ mstar,
                       const float* __restrict__ linv) {
  __shared__ half_t Alds[2][2][256 * 32];
  __shared__ half_t Blds[2][2][256 * 32];

  const int tid = threadIdx.x;
  const int lane = tid & 63;
  const int wid = tid >> 6;

  const int nx = gridDim.x;
  const int nwg = nx * gridDim.y;
  const int bid = blockIdx.y * nx + blockIdx.x;
  const int cpx = nwg >> 3;
  const int swz = (bid & 7) * cpx + (bid >> 3);
  const int rowBlk = (swz / nx) * 256;
  const int colBlk = (swz % nx) * 256;

  const int wr = (wid >> 2) * 128;
  const int wc = (wid & 3) * 64;
  const int fr = lane & 15;
  const int fs = lane >> 4;

  const int kOff = blockIdx.z * K;
  const half_t* Ag = A + (size_t)rowBlk * lda + kOff;
  const half_t* Bg = B + (size_t)colBlk * ldb + kOff;

  // MODE 2: per-lane row constants (af[mm] covers row rowBlk+wr+mm*16+fr).
  float mrow[8], irow[8];
  if (MODE == 2) {
#pragma unroll
    for (int mm = 0; mm < 8; ++mm) {
      int r = rowBlk + wr + mm * 16 + fr;
      mrow[mm] = mstar[r];  // pre-multiplied by log2e
      irow[mm] = linv[r];
    }
  }

  f32x4 acc[8][4] = {};
  const int NT = K >> 6;

  stageH(Ag, lda, Alds[0][0], tid);
  stageH(Bg, ldb, Blds[0][0], tid);
  stageH(Ag + 32, lda, Alds[0][1], tid);
  stageH(Bg + 32, ldb, Blds[0][1], tid);
  VMCNT(4);
  BAR();

  for (int kt = 0; kt < NT; ++kt) {
    const int b = kt & 1;
    const bool st = (kt + 1 < NT);
    const half_t* AgN = Ag + (kt + 1) * 64;
    const half_t* BgN = Bg + (kt + 1) * 64;

    half8 af[8], bf[4];
#pragma unroll
    for (int kh = 0; kh < 2; ++kh) {
      const half_t* Ac = Alds[b][kh];
      const half_t* Bc = Blds[b][kh];
#pragma unroll
      for (int m = 0; m < 8; ++m) {
        int row = wr + m * 16 + fr;
        af[m] = *(const half8*)(Ac + row * 32 + ((fs ^ ((row >> 1) & 3)) * 8));
      }
      if (MODE == 2) {
        // A-fragment = S values; transform to P on the fly.
#pragma unroll
        for (int m = 0; m < 8; ++m)
#pragma unroll
          for (int e = 0; e < 8; ++e) {
            float s = (float)af[m][e];
            af[m][e] = (half_t)(exp2f(s * LOG2E - mrow[m]) * irow[m]);
          }
      }
#pragma unroll
      for (int n = 0; n < 4; ++n) {
        int row = wc + n * 16 + fr;
        bf[n] = *(const half8*)(Bc + row * 32 + ((fs ^ ((row >> 1) & 3)) * 8));
      }
      if (st) {
        stageH(AgN + kh * 32, lda, Alds[b ^ 1][kh], tid);
        stageH(BgN + kh * 32, ldb, Blds[b ^ 1][kh], tid);
      }
      BAR();
      PRIO(1);
#pragma unroll
      for (int m = 0; m < 8; ++m)
#pragma unroll
        for (int n = 0; n < 4; ++n)
          acc[m][n] = MFMA(af[m], bf[n], acc[m][n]);
      PRIO(0);
      if (st) VMCNT(4);
      else if (kh == 0) VMCNT(0);
      BAR();
    }
  }

  // Epilogue. C/D mapping: col = lane&15, row = (lane>>4)*4 + j.
  const size_t zoff = (MODE == 2) ? (size_t)blockIdx.z * N_TOK * ldc : 0;
#pragma unroll
  for (int m = 0; m < 8; ++m) {
#pragma unroll
    for (int n = 0; n < 4; ++n) {
#pragma unroll
      for (int j = 0; j < 4; ++j) {
        int row = rowBlk + wr + m * 16 + (lane >> 4) * 4 + j;
        int col = colBlk + wc + n * 16 + fr;
        float v = acc[m][n][j];
        if (MODE == 0) {
          v += bias[col];
          if (col < 1024) v *= 0.125f;  // fold 1/sqrt(DK) into q
          ((half_t*)Cout)[(size_t)row * ldc + col] = (half_t)v;
        } else if (MODE == 1) {
          ((half_t*)Cout)[(size_t)row * ldc + col] = (half_t)v;
        } else {
          ((half_t*)Cout)[zoff + (size_t)row * ldc + col] = (half_t)v;
        }
      }
    }
  }

  // MODE 1: block-local softmax stats over this block's 256 cols.
  if (MODE == 1) {
    float* sM = (float*)&Alds[0][0][0];  // [4][256] m_b  (LDS dead post-loop)
    float* sL = sM + 4 * 256;            // [4][256] l_b
    const int nq = wid & 3;
    const int g = lane >> 4;
#pragma unroll
    for (int m = 0; m < 8; ++m) {
#pragma unroll
      for (int j = 0; j < 4; ++j) {
        float vmax = -1e30f;
#pragma unroll
        for (int n = 0; n < 4; ++n) vmax = fmaxf(vmax, acc[m][n][j]);
#pragma unroll
        for (int off = 1; off <= 8; off <<= 1) vmax = fmaxf(vmax, __shfl_xor(vmax, off));
        float vsum = 0.f;
#pragma unroll
        for (int n = 0; n < 4; ++n) vsum += __expf(acc[m][n][j] - vmax);
#pragma unroll
        for (int off = 1; off <= 8; off <<= 1) vsum += __shfl_xor(vsum, off);
        if (fr == 0) {
          int rl = wr + m * 16 + g * 4 + j;  // 0..255
          sM[nq * 256 + rl] = vmax;
          sL[nq * 256 + rl] = vsum;
        }
      }
    }
    BAR();
    if (tid < 256) {
      float m0 = sM[tid], m1 = sM[256 + tid], m2 = sM[512 + tid], m3 = sM[768 + tid];
      float mb = fmaxf(fmaxf(m0, m1), fmaxf(m2, m3));
      float lb = sL[tid] * __expf(m0 - mb) + sL[256 + tid] * __expf(m1 - mb) +
                 sL[512 + tid] * __expf(m2 - mb) + sL[768 + tid] * __expf(m3 - mb);
      float2 st;
      st.x = mb;
      st.y = lb;
      partials[(size_t)(rowBlk + tid) * 16 + (swz % nx)] = st;
    }
  }
}

// ---------------------------------------------------------------------------
// Combine per-block stats -> global (mstar = m* x log2e, linv = 1/l*).
// ---------------------------------------------------------------------------
__launch_bounds__(256)
__global__ void combine_stats(const float2* __restrict__ partials,
                              float* __restrict__ mstar, float* __restrict__ linv) {
  int row = blockIdx.x * 256 + threadIdx.x;
  float2 p[16];
  float m = -1e30f;
#pragma unroll
  for (int b = 0; b < 16; ++b) {
    p[b] = partials[(size_t)row * 16 + b];
    m = fmaxf(m, p[b].x);
  }
  float l = 0.f;
#pragma unroll
  for (int b = 0; b < 16; ++b) l += p[b].y * __expf(p[b].x - m);
  mstar[row] = m * LOG2E;
  linv[row] = 1.f / l;
}

// ---------------------------------------------------------------------------
// 2-phase 128x128 GEMM — small vwT GEMM only (unchanged).
// ---------------------------------------------------------------------------
template <int ROWS>
DEVI void stage32(const half_t* __restrict__ g, int ld, half_t* lbase, int tid) {
#pragma unroll
  for (int c = tid; c < ROWS * 4; c += 256) {
    int r = c >> 2;
    int k8 = ((c & 3) ^ ((r >> 1) & 3)) * 8;
    gld_lds16(g + (size_t)r * ld + k8, lbase + c * 8);
  }
}

__launch_bounds__(256, 2)
__global__ void gemm2(const half_t* __restrict__ A, int lda,
                      const half_t* __restrict__ B, int ldb,
                      half_t* __restrict__ Cout, int ldc, int K) {
  constexpr int BM = 128, BN = 128, MF = 4, NF = 4;
  __shared__ half_t At[2][BM * 32];
  __shared__ half_t Bt[2][BN * 32];

  const int tid = threadIdx.x;
  const int lane = tid & 63;
  const int wid = tid >> 6;

  const int nx = gridDim.x;
  const int nwg = nx * gridDim.y;
  const int bid = blockIdx.y * nx + blockIdx.x;
  const int cpx = nwg >> 3;
  const int swz = (bid & 7) * cpx + (bid >> 3);
  const int rowBlk = (swz / nx) * BM;
  const int colBlk = (swz % nx) * BN;

  const int wr = (wid >> 1) * (BM / 2);
  const int wc = (wid & 1) * (BN / 2);
  const int fr = lane & 15;
  const int fs = lane >> 4;

  const half_t* Ag = A + (size_t)rowBlk * lda;
  const half_t* Bg = B + (size_t)colBlk * ldb;

  f32x4 acc[MF][NF] = {};
  const int NT = K >> 5;
  stage32<BM>(Ag, lda, At[0], tid);
  stage32<BN>(Bg, ldb, Bt[0], tid);
  __syncthreads();

  int cur = 0;
  for (int t = 0; t < NT; ++t) {
    if (t + 1 < NT) {
      stage32<BM>(Ag + (t + 1) * 32, lda, At[cur ^ 1], tid);
      stage32<BN>(Bg + (t + 1) * 32, ldb, Bt[cur ^ 1], tid);
    }
    const half_t* Ac = At[cur];
    const half_t* Bc = Bt[cur];
    half8 af[MF], bf[NF];
#pragma unroll
    for (int m = 0; m < MF; ++m) {
      int row = wr + m * 16 + fr;
      af[m] = *(const half8*)(Ac + row * 32 + ((fs ^ ((row >> 1) & 3)) * 8));
    }
#pragma unroll
    for (int n = 0; n < NF; ++n) {
      int row = wc + n * 16 + fr;
      bf[n] = *(const half8*)(Bc + row * 32 + ((fs ^ ((row >> 1) & 3)) * 8));
    }
#pragma unroll
    for (int m = 0; m < MF; ++m)
#pragma unroll
      for (int n = 0; n < NF; ++n)
        acc[m][n] = MFMA(af[m], bf[n], acc[m][n]);
    __syncthreads();
    cur ^= 1;
  }

#pragma unroll
  for (int m = 0; m < MF; ++m)
#pragma unroll
    for (int n = 0; n < NF; ++n)
#pragma unroll
      for (int j = 0; j < 4; ++j) {
        int row = rowBlk + wr + m * 16 + (lane >> 4) * 4 + j;
        int col = colBlk + wc + n * 16 + fr;
        Cout[(size_t)row * ldc + col] = (half_t)acc[m][n][j];
      }
}

// ---------------------------------------------------------------------------
// Split-K reduce: out = sum of 4 fp16 partials + bias (f32 out).
// ---------------------------------------------------------------------------
__launch_bounds__(256)
__global__ void reduce_bias4(const half_t* __restrict__ p, const float* __restrict__ bias,
                             float* __restrict__ out) {
  int i = blockIdx.x * 256 + threadIdx.x;  // half8 index
  const size_t stride8 = (size_t)N_TOK * LATENT / 8;
  half8 a = ((const half8*)p)[i];
  half8 b = ((const half8*)p)[i + stride8];
  half8 c = ((const half8*)p)[i + 2 * stride8];
  half8 d = ((const half8*)p)[i + 3 * stride8];
  float4 e0 = ((const float4*)bias)[(i & 127) * 2];
  float4 e1 = ((const float4*)bias)[(i & 127) * 2 + 1];
  float r[8];
#pragma unroll
  for (int j = 0; j < 8; ++j)
    r[j] = (float)a[j] + (float)b[j] + (float)c[j] + (float)d[j];
  float4 o0, o1;
  o0.x = r[0] + e0.x; o0.y = r[1] + e0.y; o0.z = r[2] + e0.z; o0.w = r[3] + e0.w;
  o1.x = r[4] + e1.x; o1.y = r[5] + e1.y; o1.z = r[6] + e1.z; o1.w = r[7] + e1.w;
  ((float4*)out)[i * 2] = o0;
  ((float4*)out)[i * 2 + 1] = o1;
}

// ---------------------------------------------------------------------------
// Transpose [R][C] -> fp16 [C][R].
// ---------------------------------------------------------------------------
template <typename TI>
__global__ void transpose_to_f16(const TI* __restrict__ in, int ldin,
                                 half_t* __restrict__ out, int ldout) {
  __shared__ float tile[32][33];
  const int cb = blockIdx.x * 32;
  const int rb = blockIdx.y * 32;
  const int tx = threadIdx.x;
#pragma unroll
  for (int i = threadIdx.y; i < 32; i += 8)
    tile[i][tx] = (float)in[(size_t)(rb + i) * ldin + cb + tx];
  __syncthreads();
#pragma unroll
  for (int i = threadIdx.y; i < 32; i += 8)
    out[(size_t)(cb + i) * ldout + rb + tx] = (half_t)tile[tx][i];
}

__global__ void cvt_f32_f16(const float* __restrict__ in, half_t* __restrict__ out) {
  int i = blockIdx.x * 256 + threadIdx.x;
  float4 v = ((const float4*)in)[i];
  half4 h;
  h[0] = (half_t)v.x; h[1] = (half_t)v.y; h[2] = (half_t)v.z; h[3] = (half_t)v.w;
  ((half4*)out)[i] = h;
}

extern "C" void kernel_launch(void* const* d_in, const int* in_sizes, int n_in,
                              void* d_out, int out_size, void* d_ws, size_t ws_size,
                              hipStream_t stream) {
  const float* x = (const float*)d_in[0];
  const float* w_qkv = (const float*)d_in[1];
  const float* b_qkv = (const float*)d_in[2];
  const float* w_out = (const float*)d_in[3];
  const float* b_out = (const float*)d_in[4];
  float* out = (float*)d_out;

  char* ws = (char*)d_ws;
  half_t* xb    = (half_t*)(ws);
  half_t* wqkvT = (half_t*)(ws + ((size_t)8 << 20));
  half_t* qkv   = (half_t*)(ws + ((size_t)14 << 20));
  half_t* S     = (half_t*)(ws + ((size_t)46 << 20));
  float2* partials = (float2*)(ws + ((size_t)78 << 20));  // [4096][16]
  float*  mstar = (float*)(ws + ((size_t)79 << 20));
  float*  linv  = (float*)(ws + ((size_t)79 << 20) + 65536);
  half_t* vwT   = (half_t*)(ws + ((size_t)118 << 20));
  half_t* woutT = (half_t*)(ws + ((size_t)126 << 20));
  half_t* parts = (half_t*)(ws + ((size_t)14 << 20));  // qkv dead by final GEMM

  dim3 tb(32, 8);

  // 1. x -> fp16
  cvt_f32_f16<<<(N_TOK * LATENT) / (256 * 4), 256, 0, stream>>>(x, xb);
  // 2. w_qkv -> wqkvT [3072][1024] fp16
  transpose_to_f16<float><<<dim3(QKVN / 32, LATENT / 32), tb, 0, stream>>>(w_qkv, QKVN, wqkvT, LATENT);
  // 3. w_out -> woutT [1024][1024] fp16
  transpose_to_f16<float><<<dim3(LATENT / 32, LATENT / 32), tb, 0, stream>>>(w_out, LATENT, woutT, LATENT);
  // 4. qkv = x @ w_qkv + b (q scaled 0.125)  (192 blocks @ 256x256)
  gemm8h<0><<<dim3(QKVN / 256, N_TOK / 256), 512, 0, stream>>>(
      xb, LATENT, wqkvT, LATENT, qkv, QKVN, b_qkv, LATENT, nullptr, nullptr, nullptr);
  // 5. vwT[j][t] = sum_c woutT[j][c] * v[t][c]  (256 blocks @ 128x128)
  gemm2<<<dim3(N_TOK / 128, LATENT / 128), 256, 0, stream>>>(
      woutT, LATENT, qkv + 2 * LATENT, QKVN, vwT, N_TOK, LATENT);
  // 6. S = q' @ k^T + per-block softmax stats  (256 blocks @ 256x256)
  gemm8h<1><<<dim3(N_TOK / 256, N_TOK / 256), 512, 0, stream>>>(
      qkv, QKVN, qkv + LATENT, QKVN, S, N_TOK, nullptr, LATENT, partials, nullptr, nullptr);
  // 7. combine stats -> mstar (x log2e), linv
  combine_stats<<<N_TOK / 256, 256, 0, stream>>>(partials, mstar, linv);
  // 8. parts = exp2(S*log2e - mstar)*linv @ vwT, split-K=4  (4 x 64 blocks)
  gemm8h<2><<<dim3(LATENT / 256, N_TOK / 256, 4), 512, 0, stream>>>(
      S, N_TOK, vwT, N_TOK, parts, LATENT, nullptr, 1024, nullptr, mstar, linv);
  // 9. out = sum(parts) + b_out
  reduce_bias4<<<(N_TOK * LATENT) / (256 * 8), 256, 0, stream>>>(parts, b_out, out);
}

// Round 19
// 161.089 us; speedup vs baseline: 1.4789x; 1.4789x over previous
//
#include <hip/hip_runtime.h>
#include <hip/hip_fp16.h>

// MultiHeadAttention_64106681860559 — round 19: R12 exact base (best measured,
// 172.6 us) + dual-role launch fusing the two independent mid-pipeline steps:
// blocks 0-255 run the 128x128 vwT GEMM, blocks 256-4351 run one softmax row
// each. Saves the serial vwT latency (~10 us). R18's in-GEMM exp fusion reverted.
//
// Workspace (~128 MB):
//   xb fp16 [4096][1024] @0 | wqkvT fp16 [3072][1024] @8M | qkv fp16 [4096][3072] @14M
//   S fp16 [4096][4096] @46M | P fp16 [4096][4096] @78M | vwT fp16 [1024][4096] @118M
//   woutT fp16 [1024][1024] @126M | parts fp16 4x[4096][1024] @14M (qkv+S dead)

typedef _Float16 half_t;
typedef _Float16 half8 __attribute__((ext_vector_type(8)));
typedef _Float16 half4 __attribute__((ext_vector_type(4)));
typedef float f32x4 __attribute__((ext_vector_type(4)));

static constexpr int N_TOK = 4096;
static constexpr int LATENT = 1024;
static constexpr int QKVN = 3072;

#define DEVI __device__ __forceinline__
#define BAR() __builtin_amdgcn_s_barrier()
#define PRIO(x) __builtin_amdgcn_s_setprio(x)
#define VMCNT(n) asm volatile("s_waitcnt vmcnt(" #n ")" ::: "memory")

DEVI void gld_lds16(const half_t* g, half_t* l) {
  __builtin_amdgcn_global_load_lds(
      (const __attribute__((address_space(1))) void*)g,
      (__attribute__((address_space(3))) void*)l,
      16, 0, 0);
}

DEVI f32x4 MFMA(half8 a, half8 b, f32x4 c) {
  return __builtin_amdgcn_mfma_f32_16x16x32_f16(a, b, c, 0, 0, 0);
}

// ---- 64B-row swizzle (0 conflicts, R3/R9/R12-proven): phys 16B slot p of row
// r holds logical slot p ^ ((r>>1)&3). Pre-swizzled source; XOR on read.

// Stage a [256][32] fp16 half-K-tile (1024 x 16B chunks, 512 thr, 2 each).
DEVI void stageH(const half_t* __restrict__ g, int ld, half_t* lbase, int tid) {
#pragma unroll
  for (int i = 0; i < 2; ++i) {
    int c = tid + i * 512;
    int r = c >> 2;
    int k8 = ((c & 3) ^ ((r >> 1) & 3)) * 8;
    gld_lds16(g + (size_t)r * ld + k8, lbase + c * 8);
  }
}

// ---------------------------------------------------------------------------
// 256x256 GEMM (R12 schedule): 512 thr = 8 waves (2Mx4N), per-wave 128x64.
// BK=64 as two 32-wide K-halves; 2 phases/K-tile:
//  {12 ds_reads | stage A+B next-tile-same-half | BAR | prio1 | 32 MFMA |
//   prio0 | vmcnt(4) | BAR}
// MODE 0: +bias, cols<1024 * 0.125, fp16 (qkv) | MODE 1: fp16 (S) |
// MODE 2: fp16 z-sliced partials (split-K final)
// ---------------------------------------------------------------------------
template <int MODE>
__launch_bounds__(512, 2)
__global__ void gemm8h(const half_t* __restrict__ A, int lda,
                       const half_t* __restrict__ B, int ldb,
                       void* __restrict__ Cout, int ldc,
                       const float* __restrict__ bias, int K) {
  __shared__ half_t Alds[2][2][256 * 32];
  __shared__ half_t Blds[2][2][256 * 32];

  const int tid = threadIdx.x;
  const int lane = tid & 63;
  const int wid = tid >> 6;

  const int nx = gridDim.x;
  const int nwg = nx * gridDim.y;
  const int bid = blockIdx.y * nx + blockIdx.x;
  const int cpx = nwg >> 3;
  const int swz = (bid & 7) * cpx + (bid >> 3);
  const int rowBlk = (swz / nx) * 256;
  const int colBlk = (swz % nx) * 256;

  const int wr = (wid >> 2) * 128;
  const int wc = (wid & 3) * 64;
  const int fr = lane & 15;
  const int fs = lane >> 4;

  const int kOff = blockIdx.z * K;
  const half_t* Ag = A + (size_t)rowBlk * lda + kOff;
  const half_t* Bg = B + (size_t)colBlk * ldb + kOff;

  f32x4 acc[8][4] = {};
  const int NT = K >> 6;

  stageH(Ag, lda, Alds[0][0], tid);
  stageH(Bg, ldb, Blds[0][0], tid);
  stageH(Ag + 32, lda, Alds[0][1], tid);
  stageH(Bg + 32, ldb, Blds[0][1], tid);
  VMCNT(4);
  BAR();

  for (int kt = 0; kt < NT; ++kt) {
    const int b = kt & 1;
    const bool st = (kt + 1 < NT);
    const half_t* AgN = Ag + (kt + 1) * 64;
    const half_t* BgN = Bg + (kt + 1) * 64;

    half8 af[8], bf[4];
#pragma unroll
    for (int kh = 0; kh < 2; ++kh) {
      const half_t* Ac = Alds[b][kh];
      const half_t* Bc = Blds[b][kh];
#pragma unroll
      for (int m = 0; m < 8; ++m) {
        int row = wr + m * 16 + fr;
        af[m] = *(const half8*)(Ac + row * 32 + ((fs ^ ((row >> 1) & 3)) * 8));
      }
#pragma unroll
      for (int n = 0; n < 4; ++n) {
        int row = wc + n * 16 + fr;
        bf[n] = *(const half8*)(Bc + row * 32 + ((fs ^ ((row >> 1) & 3)) * 8));
      }
      if (st) {
        stageH(AgN + kh * 32, lda, Alds[b ^ 1][kh], tid);
        stageH(BgN + kh * 32, ldb, Blds[b ^ 1][kh], tid);
      }
      BAR();
      PRIO(1);
#pragma unroll
      for (int m = 0; m < 8; ++m)
#pragma unroll
        for (int n = 0; n < 4; ++n)
          acc[m][n] = MFMA(af[m], bf[n], acc[m][n]);
      PRIO(0);
      if (st) VMCNT(4);
      else if (kh == 0) VMCNT(0);
      BAR();
    }
  }

  // Epilogue. C/D mapping: col = lane&15, row = (lane>>4)*4 + j.
  const size_t zoff = (MODE == 2) ? (size_t)blockIdx.z * N_TOK * ldc : 0;
#pragma unroll
  for (int m = 0; m < 8; ++m) {
#pragma unroll
    for (int n = 0; n < 4; ++n) {
#pragma unroll
      for (int j = 0; j < 4; ++j) {
        int row = rowBlk + wr + m * 16 + (lane >> 4) * 4 + j;
        int col = colBlk + wc + n * 16 + fr;
        float v = acc[m][n][j];
        if (MODE == 0) {
          v += bias[col];
          if (col < 1024) v *= 0.125f;  // fold 1/sqrt(DK) into q
          ((half_t*)Cout)[(size_t)row * ldc + col] = (half_t)v;
        } else if (MODE == 1) {
          ((half_t*)Cout)[(size_t)row * ldc + col] = (half_t)v;
        } else {
          ((half_t*)Cout)[zoff + (size_t)row * ldc + col] = (half_t)v;
        }
      }
    }
  }
}

// ---------------------------------------------------------------------------
// Dual-role launch: blocks 0-255 = 128x128 vwT GEMM (2-phase, gemm2 logic);
// blocks 256-4351 = one softmax row each. Both 256 threads; 32KB LDS union.
// vwT: A=woutT [1024][1024], B=v (qkv+2L, QKVN-strided), C=vwT [1024][4096].
// ---------------------------------------------------------------------------
DEVI void stage32p(const half_t* __restrict__ g, int ld, half_t* lbase, int tid) {
#pragma unroll
  for (int c = tid; c < 128 * 4; c += 256) {
    int r = c >> 2;
    int k8 = ((c & 3) ^ ((r >> 1) & 3)) * 8;
    gld_lds16(g + (size_t)r * ld + k8, lbase + c * 8);
  }
}

__launch_bounds__(256, 2)
__global__ void vwt_softmax(const half_t* __restrict__ wo,
                            const half_t* __restrict__ v,
                            half_t* __restrict__ vwT,
                            const half_t* __restrict__ S,
                            half_t* __restrict__ P) {
  __shared__ __align__(16) char smem[32768];
  const int bid = blockIdx.x;
  const int tid = threadIdx.x;

  if (bid < 256) {
    // ---- vwT GEMM role (gemm2 logic, M=1024 N=4096 K=1024, 8x32 tile grid)
    constexpr int BM = 128, BN = 128, MF = 4, NF = 4;
    half_t* At = (half_t*)smem;            // [2][128*32]
    half_t* Bt = At + 2 * BM * 32;         // [2][128*32]

    const int lane = tid & 63;
    const int wid = tid >> 6;
    const int swz = (bid & 7) * 32 + (bid >> 3);  // bijective over 256
    const int rowBlk = (swz >> 5) * BM;           // 8 row tiles (LATENT)
    const int colBlk = (swz & 31) * BN;           // 32 col tiles (N_TOK)

    const int wr = (wid >> 1) * (BM / 2);
    const int wc = (wid & 1) * (BN / 2);
    const int fr = lane & 15;
    const int fs = lane >> 4;

    const half_t* Ag = wo + (size_t)rowBlk * LATENT;
    const half_t* Bg = v + (size_t)colBlk * QKVN;

    f32x4 acc[MF][NF] = {};
    const int NT = LATENT >> 5;
    stage32p(Ag, LATENT, At, tid);
    stage32p(Bg, QKVN, Bt, tid);
    __syncthreads();

    int cur = 0;
    for (int t = 0; t < NT; ++t) {
      if (t + 1 < NT) {
        stage32p(Ag + (t + 1) * 32, LATENT, At + (cur ^ 1) * BM * 32, tid);
        stage32p(Bg + (t + 1) * 32, QKVN, Bt + (cur ^ 1) * BN * 32, tid);
      }
      const half_t* Ac = At + cur * BM * 32;
      const half_t* Bc = Bt + cur * BN * 32;
      half8 af[MF], bf[NF];
#pragma unroll
      for (int m = 0; m < MF; ++m) {
        int row = wr + m * 16 + fr;
        af[m] = *(const half8*)(Ac + row * 32 + ((fs ^ ((row >> 1) & 3)) * 8));
      }
#pragma unroll
      for (int n = 0; n < NF; ++n) {
        int row = wc + n * 16 + fr;
        bf[n] = *(const half8*)(Bc + row * 32 + ((fs ^ ((row >> 1) & 3)) * 8));
      }
#pragma unroll
      for (int m = 0; m < MF; ++m)
#pragma unroll
        for (int n = 0; n < NF; ++n)
          acc[m][n] = MFMA(af[m], bf[n], acc[m][n]);
      __syncthreads();
      cur ^= 1;
    }

#pragma unroll
    for (int m = 0; m < MF; ++m)
#pragma unroll
      for (int n = 0; n < NF; ++n)
#pragma unroll
        for (int j = 0; j < 4; ++j) {
          int row = rowBlk + wr + m * 16 + (lane >> 4) * 4 + j;
          int col = colBlk + wc + n * 16 + fr;
          vwT[(size_t)row * N_TOK + col] = (half_t)acc[m][n][j];
        }
  } else {
    // ---- softmax role: one row of S -> P
    const int row = bid - 256;
    float* redm = (float*)smem;
    float* reds = redm + 4;
    const half8* s8 = (const half8*)(S + (size_t)row * N_TOK);

    half8 vv[2];
    float lmax = -1e30f;
#pragma unroll
    for (int i = 0; i < 2; ++i) {
      vv[i] = s8[tid + i * 256];
#pragma unroll
      for (int j = 0; j < 8; ++j) lmax = fmaxf(lmax, (float)vv[i][j]);
    }
#pragma unroll
    for (int off = 32; off; off >>= 1) lmax = fmaxf(lmax, __shfl_xor(lmax, off));
    if ((tid & 63) == 0) redm[tid >> 6] = lmax;
    __syncthreads();
    lmax = fmaxf(fmaxf(redm[0], redm[1]), fmaxf(redm[2], redm[3]));

    float e[16];
    float lsum = 0.f;
#pragma unroll
    for (int i = 0; i < 2; ++i)
#pragma unroll
      for (int j = 0; j < 8; ++j) {
        float ev = __expf((float)vv[i][j] - lmax);
        e[i * 8 + j] = ev;
        lsum += ev;
      }
#pragma unroll
    for (int off = 32; off; off >>= 1) lsum += __shfl_xor(lsum, off);
    if ((tid & 63) == 0) reds[tid >> 6] = lsum;
    __syncthreads();
    float inv = 1.f / (reds[0] + reds[1] + reds[2] + reds[3]);

    half8* p8 = (half8*)(P + (size_t)row * N_TOK);
#pragma unroll
    for (int i = 0; i < 2; ++i) {
      half8 h;
#pragma unroll
      for (int j = 0; j < 8; ++j) h[j] = (half_t)(e[i * 8 + j] * inv);
      p8[tid + i * 256] = h;
    }
  }
}

// ---------------------------------------------------------------------------
// Split-K reduce: out = sum of 4 fp16 partials + bias (f32 out).
// ---------------------------------------------------------------------------
__launch_bounds__(256)
__global__ void reduce_bias4(const half_t* __restrict__ p, const float* __restrict__ bias,
                             float* __restrict__ out) {
  int i = blockIdx.x * 256 + threadIdx.x;  // half8 index
  const size_t stride8 = (size_t)N_TOK * LATENT / 8;
  half8 a = ((const half8*)p)[i];
  half8 b = ((const half8*)p)[i + stride8];
  half8 c = ((const half8*)p)[i + 2 * stride8];
  half8 d = ((const half8*)p)[i + 3 * stride8];
  float4 e0 = ((const float4*)bias)[(i & 127) * 2];
  float4 e1 = ((const float4*)bias)[(i & 127) * 2 + 1];
  float r[8];
#pragma unroll
  for (int j = 0; j < 8; ++j)
    r[j] = (float)a[j] + (float)b[j] + (float)c[j] + (float)d[j];
  float4 o0, o1;
  o0.x = r[0] + e0.x; o0.y = r[1] + e0.y; o0.z = r[2] + e0.z; o0.w = r[3] + e0.w;
  o1.x = r[4] + e1.x; o1.y = r[5] + e1.y; o1.z = r[6] + e1.z; o1.w = r[7] + e1.w;
  ((float4*)out)[i * 2] = o0;
  ((float4*)out)[i * 2 + 1] = o1;
}

// ---------------------------------------------------------------------------
// Transpose [R][C] -> fp16 [C][R].
// ---------------------------------------------------------------------------
template <typename TI>
__global__ void transpose_to_f16(const TI* __restrict__ in, int ldin,
                                 half_t* __restrict__ out, int ldout) {
  __shared__ float tile[32][33];
  const int cb = blockIdx.x * 32;
  const int rb = blockIdx.y * 32;
  const int tx = threadIdx.x;
#pragma unroll
  for (int i = threadIdx.y; i < 32; i += 8)
    tile[i][tx] = (float)in[(size_t)(rb + i) * ldin + cb + tx];
  __syncthreads();
#pragma unroll
  for (int i = threadIdx.y; i < 32; i += 8)
    out[(size_t)(cb + i) * ldout + rb + tx] = (half_t)tile[tx][i];
}

__global__ void cvt_f32_f16(const float* __restrict__ in, half_t* __restrict__ out) {
  int i = blockIdx.x * 256 + threadIdx.x;
  float4 v = ((const float4*)in)[i];
  half4 h;
  h[0] = (half_t)v.x; h[1] = (half_t)v.y; h[2] = (half_t)v.z; h[3] = (half_t)v.w;
  ((half4*)out)[i] = h;
}

extern "C" void kernel_launch(void* const* d_in, const int* in_sizes, int n_in,
                              void* d_out, int out_size, void* d_ws, size_t ws_size,
                              hipStream_t stream) {
  const float* x = (const float*)d_in[0];
  const float* w_qkv = (const float*)d_in[1];
  const float* b_qkv = (const float*)d_in[2];
  const float* w_out = (const float*)d_in[3];
  const float* b_out = (const float*)d_in[4];
  float* out = (float*)d_out;

  char* ws = (char*)d_ws;
  half_t* xb    = (half_t*)(ws);
  half_t* wqkvT = (half_t*)(ws + ((size_t)8 << 20));
  half_t* qkv   = (half_t*)(ws + ((size_t)14 << 20));
  half_t* S     = (half_t*)(ws + ((size_t)46 << 20));
  half_t* P     = (half_t*)(ws + ((size_t)78 << 20));
  half_t* vwT   = (half_t*)(ws + ((size_t)118 << 20));
  half_t* woutT = (half_t*)(ws + ((size_t)126 << 20));
  half_t* parts = (half_t*)(ws + ((size_t)14 << 20));  // qkv+S dead by then

  dim3 tb(32, 8);

  // 1. x -> fp16
  cvt_f32_f16<<<(N_TOK * LATENT) / (256 * 4), 256, 0, stream>>>(x, xb);
  // 2. w_qkv -> wqkvT [3072][1024] fp16
  transpose_to_f16<float><<<dim3(QKVN / 32, LATENT / 32), tb, 0, stream>>>(w_qkv, QKVN, wqkvT, LATENT);
  // 3. w_out -> woutT [1024][1024] fp16
  transpose_to_f16<float><<<dim3(LATENT / 32, LATENT / 32), tb, 0, stream>>>(w_out, LATENT, woutT, LATENT);
  // 4. qkv = x @ w_qkv + b (q scaled 0.125)  (192 blocks @ 256x256)
  gemm8h<0><<<dim3(QKVN / 256, N_TOK / 256), 512, 0, stream>>>(
      xb, LATENT, wqkvT, LATENT, qkv, QKVN, b_qkv, LATENT);
  // 5. S = q' @ k^T  (256 blocks @ 256x256)
  gemm8h<1><<<dim3(N_TOK / 256, N_TOK / 256), 512, 0, stream>>>(
      qkv, QKVN, qkv + LATENT, QKVN, S, N_TOK, nullptr, LATENT);
  // 6. dual-role: vwT GEMM (256 blocks) + softmax rows (4096 blocks)
  vwt_softmax<<<256 + N_TOK, 256, 0, stream>>>(
      woutT, qkv + 2 * LATENT, vwT, S, P);
  // 7. parts = P @ vwT, split-K=4, fp16 partials  (4 x 64 blocks @ 256x256)
  gemm8h<2><<<dim3(LATENT / 256, N_TOK / 256, 4), 512, 0, stream>>>(
      P, N_TOK, vwT, N_TOK, parts, LATENT, nullptr, 1024);
  // 8. out = sum(parts) + b_out
  reduce_bias4<<<(N_TOK * LATENT) / (256 * 8), 256, 0, stream>>>(parts, b_out, out);
}

// Round 22
// 155.655 us; speedup vs baseline: 1.5305x; 1.0349x over previous
//
#include <hip/hip_runtime.h>
#include <hip/hip_fp16.h>

// MultiHeadAttention_64106681860559 — round 22: R19 base (best passing, 161.1us)
// + single preamble launch, FIXED grid: cvt needs 4096 blocks (R21 gave 1024 ->
// 3/4 of xb left poisoned). Roles: [0,4096) cvt x; [4096,7168) transpose w_qkv;
// [7168,8192) transpose w_out.
//
// Workspace (~128 MB):
//   xb fp16 [4096][1024] @0 | wqkvT fp16 [3072][1024] @8M | qkv fp16 [4096][3072] @14M
//   S fp16 [4096][4096] @46M | P fp16 [4096][4096] @78M | vwT fp16 [1024][4096] @118M
//   woutT fp16 [1024][1024] @126M | parts fp16 4x[4096][1024] @14M (qkv+S dead)

typedef _Float16 half_t;
typedef _Float16 half8 __attribute__((ext_vector_type(8)));
typedef _Float16 half4 __attribute__((ext_vector_type(4)));
typedef float f32x4 __attribute__((ext_vector_type(4)));

static constexpr int N_TOK = 4096;
static constexpr int LATENT = 1024;
static constexpr int QKVN = 3072;

#define DEVI __device__ __forceinline__
#define BAR() __builtin_amdgcn_s_barrier()
#define PRIO(x) __builtin_amdgcn_s_setprio(x)
#define VMCNT(n) asm volatile("s_waitcnt vmcnt(" #n ")" ::: "memory")

DEVI void gld_lds16(const half_t* g, half_t* l) {
  __builtin_amdgcn_global_load_lds(
      (const __attribute__((address_space(1))) void*)g,
      (__attribute__((address_space(3))) void*)l,
      16, 0, 0);
}

DEVI f32x4 MFMA(half8 a, half8 b, f32x4 c) {
  return __builtin_amdgcn_mfma_f32_16x16x32_f16(a, b, c, 0, 0, 0);
}

// ---- 64B-row swizzle (0 conflicts, proven): phys 16B slot p of row r holds
// logical slot p ^ ((r>>1)&3). Pre-swizzled source; XOR on read.

// Stage a [256][32] fp16 half-K-tile (1024 x 16B chunks, 512 thr, 2 each).
DEVI void stageH(const half_t* __restrict__ g, int ld, half_t* lbase, int tid) {
#pragma unroll
  for (int i = 0; i < 2; ++i) {
    int c = tid + i * 512;
    int r = c >> 2;
    int k8 = ((c & 3) ^ ((r >> 1) & 3)) * 8;
    gld_lds16(g + (size_t)r * ld + k8, lbase + c * 8);
  }
}

// ---------------------------------------------------------------------------
// 256x256 GEMM (R12 schedule): 512 thr = 8 waves (2Mx4N), per-wave 128x64.
// BK=64 as two 32-wide K-halves; 2 phases/K-tile:
//  {12 ds_reads | stage A+B next-tile-same-half | BAR | prio1 | 32 MFMA |
//   prio0 | vmcnt(4) | BAR}
// MODE 0: +bias, cols<1024 * 0.125, fp16 (qkv) | MODE 1: fp16 (S) |
// MODE 2: fp16 z-sliced partials (split-K final)
// ---------------------------------------------------------------------------
template <int MODE>
__launch_bounds__(512, 2)
__global__ void gemm8h(const half_t* __restrict__ A, int lda,
                       const half_t* __restrict__ B, int ldb,
                       void* __restrict__ Cout, int ldc,
                       const float* __restrict__ bias, int K) {
  __shared__ half_t Alds[2][2][256 * 32];
  __shared__ half_t Blds[2][2][256 * 32];

  const int tid = threadIdx.x;
  const int lane = tid & 63;
  const int wid = tid >> 6;

  const int nx = gridDim.x;
  const int nwg = nx * gridDim.y;
  const int bid = blockIdx.y * nx + blockIdx.x;
  const int cpx = nwg >> 3;
  const int swz = (bid & 7) * cpx + (bid >> 3);
  const int rowBlk = (swz / nx) * 256;
  const int colBlk = (swz % nx) * 256;

  const int wr = (wid >> 2) * 128;
  const int wc = (wid & 3) * 64;
  const int fr = lane & 15;
  const int fs = lane >> 4;

  const int kOff = blockIdx.z * K;
  const half_t* Ag = A + (size_t)rowBlk * lda + kOff;
  const half_t* Bg = B + (size_t)colBlk * ldb + kOff;

  f32x4 acc[8][4] = {};
  const int NT = K >> 6;

  stageH(Ag, lda, Alds[0][0], tid);
  stageH(Bg, ldb, Blds[0][0], tid);
  stageH(Ag + 32, lda, Alds[0][1], tid);
  stageH(Bg + 32, ldb, Blds[0][1], tid);
  VMCNT(4);
  BAR();

  for (int kt = 0; kt < NT; ++kt) {
    const int b = kt & 1;
    const bool st = (kt + 1 < NT);
    const half_t* AgN = Ag + (kt + 1) * 64;
    const half_t* BgN = Bg + (kt + 1) * 64;

    half8 af[8], bf[4];
#pragma unroll
    for (int kh = 0; kh < 2; ++kh) {
      const half_t* Ac = Alds[b][kh];
      const half_t* Bc = Blds[b][kh];
#pragma unroll
      for (int m = 0; m < 8; ++m) {
        int row = wr + m * 16 + fr;
        af[m] = *(const half8*)(Ac + row * 32 + ((fs ^ ((row >> 1) & 3)) * 8));
      }
#pragma unroll
      for (int n = 0; n < 4; ++n) {
        int row = wc + n * 16 + fr;
        bf[n] = *(const half8*)(Bc + row * 32 + ((fs ^ ((row >> 1) & 3)) * 8));
      }
      if (st) {
        stageH(AgN + kh * 32, lda, Alds[b ^ 1][kh], tid);
        stageH(BgN + kh * 32, ldb, Blds[b ^ 1][kh], tid);
      }
      BAR();
      PRIO(1);
#pragma unroll
      for (int m = 0; m < 8; ++m)
#pragma unroll
        for (int n = 0; n < 4; ++n)
          acc[m][n] = MFMA(af[m], bf[n], acc[m][n]);
      PRIO(0);
      if (st) VMCNT(4);
      else if (kh == 0) VMCNT(0);
      BAR();
    }
  }

  // Epilogue. C/D mapping: col = lane&15, row = (lane>>4)*4 + j.
  const size_t zoff = (MODE == 2) ? (size_t)blockIdx.z * N_TOK * ldc : 0;
#pragma unroll
  for (int m = 0; m < 8; ++m) {
#pragma unroll
    for (int n = 0; n < 4; ++n) {
#pragma unroll
      for (int j = 0; j < 4; ++j) {
        int row = rowBlk + wr + m * 16 + (lane >> 4) * 4 + j;
        int col = colBlk + wc + n * 16 + fr;
        float v = acc[m][n][j];
        if (MODE == 0) {
          v += bias[col];
          if (col < 1024) v *= 0.125f;  // fold 1/sqrt(DK) into q
          ((half_t*)Cout)[(size_t)row * ldc + col] = (half_t)v;
        } else if (MODE == 1) {
          ((half_t*)Cout)[(size_t)row * ldc + col] = (half_t)v;
        } else {
          ((half_t*)Cout)[zoff + (size_t)row * ldc + col] = (half_t)v;
        }
      }
    }
  }
}

// ---------------------------------------------------------------------------
// Dual-role launch: blocks 0-255 = 128x128 vwT GEMM; blocks 256-4351 = one
// softmax row each (unchanged from R19).
// ---------------------------------------------------------------------------
DEVI void stage32p(const half_t* __restrict__ g, int ld, half_t* lbase, int tid) {
#pragma unroll
  for (int c = tid; c < 128 * 4; c += 256) {
    int r = c >> 2;
    int k8 = ((c & 3) ^ ((r >> 1) & 3)) * 8;
    gld_lds16(g + (size_t)r * ld + k8, lbase + c * 8);
  }
}

__launch_bounds__(256, 2)
__global__ void vwt_softmax(const half_t* __restrict__ wo,
                            const half_t* __restrict__ v,
                            half_t* __restrict__ vwT,
                            const half_t* __restrict__ S,
                            half_t* __restrict__ P) {
  __shared__ __align__(16) char smem[32768];
  const int bid = blockIdx.x;
  const int tid = threadIdx.x;

  if (bid < 256) {
    constexpr int BM = 128, BN = 128, MF = 4, NF = 4;
    half_t* At = (half_t*)smem;
    half_t* Bt = At + 2 * BM * 32;

    const int lane = tid & 63;
    const int wid = tid >> 6;
    const int swz = (bid & 7) * 32 + (bid >> 3);
    const int rowBlk = (swz >> 5) * BM;
    const int colBlk = (swz & 31) * BN;

    const int wr = (wid >> 1) * (BM / 2);
    const int wc = (wid & 1) * (BN / 2);
    const int fr = lane & 15;
    const int fs = lane >> 4;

    const half_t* Ag = wo + (size_t)rowBlk * LATENT;
    const half_t* Bg = v + (size_t)colBlk * QKVN;

    f32x4 acc[MF][NF] = {};
    const int NT = LATENT >> 5;
    stage32p(Ag, LATENT, At, tid);
    stage32p(Bg, QKVN, Bt, tid);
    __syncthreads();

    int cur = 0;
    for (int t = 0; t < NT; ++t) {
      if (t + 1 < NT) {
        stage32p(Ag + (t + 1) * 32, LATENT, At + (cur ^ 1) * BM * 32, tid);
        stage32p(Bg + (t + 1) * 32, QKVN, Bt + (cur ^ 1) * BN * 32, tid);
      }
      const half_t* Ac = At + cur * BM * 32;
      const half_t* Bc = Bt + cur * BN * 32;
      half8 af[MF], bf[NF];
#pragma unroll
      for (int m = 0; m < MF; ++m) {
        int row = wr + m * 16 + fr;
        af[m] = *(const half8*)(Ac + row * 32 + ((fs ^ ((row >> 1) & 3)) * 8));
      }
#pragma unroll
      for (int n = 0; n < NF; ++n) {
        int row = wc + n * 16 + fr;
        bf[n] = *(const half8*)(Bc + row * 32 + ((fs ^ ((row >> 1) & 3)) * 8));
      }
#pragma unroll
      for (int m = 0; m < MF; ++m)
#pragma unroll
        for (int n = 0; n < NF; ++n)
          acc[m][n] = MFMA(af[m], bf[n], acc[m][n]);
      __syncthreads();
      cur ^= 1;
    }

#pragma unroll
    for (int m = 0; m < MF; ++m)
#pragma unroll
      for (int n = 0; n < NF; ++n)
#pragma unroll
        for (int j = 0; j < 4; ++j) {
          int row = rowBlk + wr + m * 16 + (lane >> 4) * 4 + j;
          int col = colBlk + wc + n * 16 + fr;
          vwT[(size_t)row * N_TOK + col] = (half_t)acc[m][n][j];
        }
  } else {
    const int row = bid - 256;
    float* redm = (float*)smem;
    float* reds = redm + 4;
    const half8* s8 = (const half8*)(S + (size_t)row * N_TOK);

    half8 vv[2];
    float lmax = -1e30f;
#pragma unroll
    for (int i = 0; i < 2; ++i) {
      vv[i] = s8[tid + i * 256];
#pragma unroll
      for (int j = 0; j < 8; ++j) lmax = fmaxf(lmax, (float)vv[i][j]);
    }
#pragma unroll
    for (int off = 32; off; off >>= 1) lmax = fmaxf(lmax, __shfl_xor(lmax, off));
    if ((tid & 63) == 0) redm[tid >> 6] = lmax;
    __syncthreads();
    lmax = fmaxf(fmaxf(redm[0], redm[1]), fmaxf(redm[2], redm[3]));

    float e[16];
    float lsum = 0.f;
#pragma unroll
    for (int i = 0; i < 2; ++i)
#pragma unroll
      for (int j = 0; j < 8; ++j) {
        float ev = __expf((float)vv[i][j] - lmax);
        e[i * 8 + j] = ev;
        lsum += ev;
      }
#pragma unroll
    for (int off = 32; off; off >>= 1) lsum += __shfl_xor(lsum, off);
    if ((tid & 63) == 0) reds[tid >> 6] = lsum;
    __syncthreads();
    float inv = 1.f / (reds[0] + reds[1] + reds[2] + reds[3]);

    half8* p8 = (half8*)(P + (size_t)row * N_TOK);
#pragma unroll
    for (int i = 0; i < 2; ++i) {
      half8 h;
#pragma unroll
      for (int j = 0; j < 8; ++j) h[j] = (half_t)(e[i * 8 + j] * inv);
      p8[tid + i * 256] = h;
    }
  }
}

// ---------------------------------------------------------------------------
// Split-K reduce: out = sum of 4 fp16 partials + bias (f32 out).
// ---------------------------------------------------------------------------
__launch_bounds__(256)
__global__ void reduce_bias4(const half_t* __restrict__ p, const float* __restrict__ bias,
                             float* __restrict__ out) {
  int i = blockIdx.x * 256 + threadIdx.x;  // half8 index
  const size_t stride8 = (size_t)N_TOK * LATENT / 8;
  half8 a = ((const half8*)p)[i];
  half8 b = ((const half8*)p)[i + stride8];
  half8 c = ((const half8*)p)[i + 2 * stride8];
  half8 d = ((const half8*)p)[i + 3 * stride8];
  float4 e0 = ((const float4*)bias)[(i & 127) * 2];
  float4 e1 = ((const float4*)bias)[(i & 127) * 2 + 1];
  float r[8];
#pragma unroll
  for (int j = 0; j < 8; ++j)
    r[j] = (float)a[j] + (float)b[j] + (float)c[j] + (float)d[j];
  float4 o0, o1;
  o0.x = r[0] + e0.x; o0.y = r[1] + e0.y; o0.z = r[2] + e0.z; o0.w = r[3] + e0.w;
  o1.x = r[4] + e1.x; o1.y = r[5] + e1.y; o1.z = r[6] + e1.z; o1.w = r[7] + e1.w;
  ((float4*)out)[i * 2] = o0;
  ((float4*)out)[i * 2 + 1] = o1;
}

// ---------------------------------------------------------------------------
// Preamble (single launch, 8192 blocks): [0,4096) cvt x->fp16 (1M float4s);
// [4096,7168) transpose w_qkv (96x32 tiles); [7168,8192) transpose w_out.
// ---------------------------------------------------------------------------
DEVI void tr32(const float* __restrict__ in, int ldin,
               half_t* __restrict__ out, int ldout,
               int cb, int rb, int tid, float (*tile)[33]) {
  const int tx = tid & 31;
  const int ty = tid >> 5;
#pragma unroll
  for (int i = ty; i < 32; i += 8)
    tile[i][tx] = in[(size_t)(rb + i) * ldin + cb + tx];
  __syncthreads();
#pragma unroll
  for (int i = ty; i < 32; i += 8)
    out[(size_t)(cb + i) * ldout + rb + tx] = (half_t)tile[tx][i];
}

__launch_bounds__(256)
__global__ void preamble(const float* __restrict__ x, half_t* __restrict__ xb,
                         const float* __restrict__ wq, half_t* __restrict__ wqT,
                         const float* __restrict__ wo, half_t* __restrict__ woT) {
  __shared__ float tile[32][33];
  const int bid = blockIdx.x;
  const int tid = threadIdx.x;
  if (bid < 4096) {
    int i = bid * 256 + tid;  // float4 index, 4096*256 = 1M = all of x
    float4 v = ((const float4*)x)[i];
    half4 h;
    h[0] = (half_t)v.x; h[1] = (half_t)v.y; h[2] = (half_t)v.z; h[3] = (half_t)v.w;
    ((half4*)xb)[i] = h;
  } else if (bid < 7168) {
    int l = bid - 4096;  // 3072 tiles: 96 cols x 32 rows
    tr32(wq, QKVN, wqT, LATENT, (l % 96) * 32, (l / 96) * 32, tid, tile);
  } else {
    int l = bid - 7168;  // 1024 tiles: 32 x 32
    tr32(wo, LATENT, woT, LATENT, (l & 31) * 32, (l >> 5) * 32, tid, tile);
  }
}

extern "C" void kernel_launch(void* const* d_in, const int* in_sizes, int n_in,
                              void* d_out, int out_size, void* d_ws, size_t ws_size,
                              hipStream_t stream) {
  const float* x = (const float*)d_in[0];
  const float* w_qkv = (const float*)d_in[1];
  const float* b_qkv = (const float*)d_in[2];
  const float* w_out = (const float*)d_in[3];
  const float* b_out = (const float*)d_in[4];
  float* out = (float*)d_out;

  char* ws = (char*)d_ws;
  half_t* xb    = (half_t*)(ws);
  half_t* wqkvT = (half_t*)(ws + ((size_t)8 << 20));
  half_t* qkv   = (half_t*)(ws + ((size_t)14 << 20));
  half_t* S     = (half_t*)(ws + ((size_t)46 << 20));
  half_t* P     = (half_t*)(ws + ((size_t)78 << 20));
  half_t* vwT   = (half_t*)(ws + ((size_t)118 << 20));
  half_t* woutT = (half_t*)(ws + ((size_t)126 << 20));
  half_t* parts = (half_t*)(ws + ((size_t)14 << 20));  // qkv+S dead by then

  // 1. preamble: cvt + both transposes in one launch (8192 blocks)
  preamble<<<8192, 256, 0, stream>>>(x, xb, w_qkv, wqkvT, w_out, woutT);
  // 2. qkv = x @ w_qkv + b (q scaled 0.125)  (192 blocks @ 256x256)
  gemm8h<0><<<dim3(QKVN / 256, N_TOK / 256), 512, 0, stream>>>(
      xb, LATENT, wqkvT, LATENT, qkv, QKVN, b_qkv, LATENT);
  // 3. S = q' @ k^T  (256 blocks @ 256x256)
  gemm8h<1><<<dim3(N_TOK / 256, N_TOK / 256), 512, 0, stream>>>(
      qkv, QKVN, qkv + LATENT, QKVN, S, N_TOK, nullptr, LATENT);
  // 4. dual-role: vwT GEMM (256 blocks) + softmax rows (4096 blocks)
  vwt_softmax<<<256 + N_TOK, 256, 0, stream>>>(
      woutT, qkv + 2 * LATENT, vwT, S, P);
  // 5. parts = P @ vwT, split-K=4, fp16 partials  (4 x 64 blocks @ 256x256)
  gemm8h<2><<<dim3(LATENT / 256, N_TOK / 256, 4), 512, 0, stream>>>(
      P, N_TOK, vwT, N_TOK, parts, LATENT, nullptr, 1024);
  // 6. out = sum(parts) + b_out
  reduce_bias4<<<(N_TOK * LATENT) / (256 * 8), 256, 0, stream>>>(parts, b_out, out);
}

// Round 23
// 149.853 us; speedup vs baseline: 1.5898x; 1.0387x over previous
//
#include <hip/hip_runtime.h>
#include <hip/hip_fp16.h>

// MultiHeadAttention_64106681860559 — round 23: R22 base (best, 155.7 us) with
// the provably-redundant pre-MFMA barrier removed from gemm8h (2 barriers per
// K-tile instead of 4). Hazards: RAW covered by previous phase's vmcnt(4)+BAR;
// WAR covered by one-barrier-per-phase wave-drift bound. Tail logic unchanged.
//
// Workspace (~128 MB):
//   xb fp16 [4096][1024] @0 | wqkvT fp16 [3072][1024] @8M | qkv fp16 [4096][3072] @14M
//   S fp16 [4096][4096] @46M | P fp16 [4096][4096] @78M | vwT fp16 [1024][4096] @118M
//   woutT fp16 [1024][1024] @126M | parts fp16 4x[4096][1024] @14M (qkv+S dead)

typedef _Float16 half_t;
typedef _Float16 half8 __attribute__((ext_vector_type(8)));
typedef _Float16 half4 __attribute__((ext_vector_type(4)));
typedef float f32x4 __attribute__((ext_vector_type(4)));

static constexpr int N_TOK = 4096;
static constexpr int LATENT = 1024;
static constexpr int QKVN = 3072;

#define DEVI __device__ __forceinline__
#define BAR() __builtin_amdgcn_s_barrier()
#define PRIO(x) __builtin_amdgcn_s_setprio(x)
#define VMCNT(n) asm volatile("s_waitcnt vmcnt(" #n ")" ::: "memory")

DEVI void gld_lds16(const half_t* g, half_t* l) {
  __builtin_amdgcn_global_load_lds(
      (const __attribute__((address_space(1))) void*)g,
      (__attribute__((address_space(3))) void*)l,
      16, 0, 0);
}

DEVI f32x4 MFMA(half8 a, half8 b, f32x4 c) {
  return __builtin_amdgcn_mfma_f32_16x16x32_f16(a, b, c, 0, 0, 0);
}

// ---- 64B-row swizzle (0 conflicts, proven): phys 16B slot p of row r holds
// logical slot p ^ ((r>>1)&3). Pre-swizzled source; XOR on read.

// Stage a [256][32] fp16 half-K-tile (1024 x 16B chunks, 512 thr, 2 each).
DEVI void stageH(const half_t* __restrict__ g, int ld, half_t* lbase, int tid) {
#pragma unroll
  for (int i = 0; i < 2; ++i) {
    int c = tid + i * 512;
    int r = c >> 2;
    int k8 = ((c & 3) ^ ((r >> 1) & 3)) * 8;
    gld_lds16(g + (size_t)r * ld + k8, lbase + c * 8);
  }
}

// ---------------------------------------------------------------------------
// 256x256 GEMM: 512 thr = 8 waves (2Mx4N), per-wave 128x64 (acc[8][4]).
// BK=64 as two 32-wide K-halves; 2 phases/K-tile, ONE barrier per phase:
//  {12 ds_reads | stage A+B next-tile-same-half | prio1 | 32 MFMA | prio0 |
//   vmcnt(4) | BAR}
// MODE 0: +bias, cols<1024 * 0.125, fp16 (qkv) | MODE 1: fp16 (S) |
// MODE 2: fp16 z-sliced partials (split-K final)
// ---------------------------------------------------------------------------
template <int MODE>
__launch_bounds__(512, 2)
__global__ void gemm8h(const half_t* __restrict__ A, int lda,
                       const half_t* __restrict__ B, int ldb,
                       void* __restrict__ Cout, int ldc,
                       const float* __restrict__ bias, int K) {
  __shared__ half_t Alds[2][2][256 * 32];
  __shared__ half_t Blds[2][2][256 * 32];

  const int tid = threadIdx.x;
  const int lane = tid & 63;
  const int wid = tid >> 6;

  const int nx = gridDim.x;
  const int nwg = nx * gridDim.y;
  const int bid = blockIdx.y * nx + blockIdx.x;
  const int cpx = nwg >> 3;
  const int swz = (bid & 7) * cpx + (bid >> 3);
  const int rowBlk = (swz / nx) * 256;
  const int colBlk = (swz % nx) * 256;

  const int wr = (wid >> 2) * 128;
  const int wc = (wid & 3) * 64;
  const int fr = lane & 15;
  const int fs = lane >> 4;

  const int kOff = blockIdx.z * K;
  const half_t* Ag = A + (size_t)rowBlk * lda + kOff;
  const half_t* Bg = B + (size_t)colBlk * ldb + kOff;

  f32x4 acc[8][4] = {};
  const int NT = K >> 6;

  stageH(Ag, lda, Alds[0][0], tid);
  stageH(Bg, ldb, Blds[0][0], tid);
  stageH(Ag + 32, lda, Alds[0][1], tid);
  stageH(Bg + 32, ldb, Blds[0][1], tid);
  VMCNT(4);
  BAR();

  for (int kt = 0; kt < NT; ++kt) {
    const int b = kt & 1;
    const bool st = (kt + 1 < NT);
    const half_t* AgN = Ag + (kt + 1) * 64;
    const half_t* BgN = Bg + (kt + 1) * 64;

    half8 af[8], bf[4];
#pragma unroll
    for (int kh = 0; kh < 2; ++kh) {
      const half_t* Ac = Alds[b][kh];
      const half_t* Bc = Blds[b][kh];
#pragma unroll
      for (int m = 0; m < 8; ++m) {
        int row = wr + m * 16 + fr;
        af[m] = *(const half8*)(Ac + row * 32 + ((fs ^ ((row >> 1) & 3)) * 8));
      }
#pragma unroll
      for (int n = 0; n < 4; ++n) {
        int row = wc + n * 16 + fr;
        bf[n] = *(const half8*)(Bc + row * 32 + ((fs ^ ((row >> 1) & 3)) * 8));
      }
      if (st) {
        stageH(AgN + kh * 32, lda, Alds[b ^ 1][kh], tid);
        stageH(BgN + kh * 32, ldb, Blds[b ^ 1][kh], tid);
      }
      // (pre-MFMA barrier removed: RAW covered by previous phase's vmcnt+BAR;
      //  WAR covered by one-barrier-per-phase drift bound)
      PRIO(1);
#pragma unroll
      for (int m = 0; m < 8; ++m)
#pragma unroll
        for (int n = 0; n < 4; ++n)
          acc[m][n] = MFMA(af[m], bf[n], acc[m][n]);
      PRIO(0);
      if (st) VMCNT(4);
      else if (kh == 0) VMCNT(0);
      BAR();
    }
  }

  // Epilogue. C/D mapping: col = lane&15, row = (lane>>4)*4 + j.
  const size_t zoff = (MODE == 2) ? (size_t)blockIdx.z * N_TOK * ldc : 0;
#pragma unroll
  for (int m = 0; m < 8; ++m) {
#pragma unroll
    for (int n = 0; n < 4; ++n) {
#pragma unroll
      for (int j = 0; j < 4; ++j) {
        int row = rowBlk + wr + m * 16 + (lane >> 4) * 4 + j;
        int col = colBlk + wc + n * 16 + fr;
        float v = acc[m][n][j];
        if (MODE == 0) {
          v += bias[col];
          if (col < 1024) v *= 0.125f;  // fold 1/sqrt(DK) into q
          ((half_t*)Cout)[(size_t)row * ldc + col] = (half_t)v;
        } else if (MODE == 1) {
          ((half_t*)Cout)[(size_t)row * ldc + col] = (half_t)v;
        } else {
          ((half_t*)Cout)[zoff + (size_t)row * ldc + col] = (half_t)v;
        }
      }
    }
  }
}

// ---------------------------------------------------------------------------
// Dual-role launch: blocks 0-255 = 128x128 vwT GEMM; blocks 256-4351 = one
// softmax row each (unchanged from R19/R22).
// ---------------------------------------------------------------------------
DEVI void stage32p(const half_t* __restrict__ g, int ld, half_t* lbase, int tid) {
#pragma unroll
  for (int c = tid; c < 128 * 4; c += 256) {
    int r = c >> 2;
    int k8 = ((c & 3) ^ ((r >> 1) & 3)) * 8;
    gld_lds16(g + (size_t)r * ld + k8, lbase + c * 8);
  }
}

__launch_bounds__(256, 2)
__global__ void vwt_softmax(const half_t* __restrict__ wo,
                            const half_t* __restrict__ v,
                            half_t* __restrict__ vwT,
                            const half_t* __restrict__ S,
                            half_t* __restrict__ P) {
  __shared__ __align__(16) char smem[32768];
  const int bid = blockIdx.x;
  const int tid = threadIdx.x;

  if (bid < 256) {
    constexpr int BM = 128, BN = 128, MF = 4, NF = 4;
    half_t* At = (half_t*)smem;
    half_t* Bt = At + 2 * BM * 32;

    const int lane = tid & 63;
    const int wid = tid >> 6;
    const int swz = (bid & 7) * 32 + (bid >> 3);
    const int rowBlk = (swz >> 5) * BM;
    const int colBlk = (swz & 31) * BN;

    const int wr = (wid >> 1) * (BM / 2);
    const int wc = (wid & 1) * (BN / 2);
    const int fr = lane & 15;
    const int fs = lane >> 4;

    const half_t* Ag = wo + (size_t)rowBlk * LATENT;
    const half_t* Bg = v + (size_t)colBlk * QKVN;

    f32x4 acc[MF][NF] = {};
    const int NT = LATENT >> 5;
    stage32p(Ag, LATENT, At, tid);
    stage32p(Bg, QKVN, Bt, tid);
    __syncthreads();

    int cur = 0;
    for (int t = 0; t < NT; ++t) {
      if (t + 1 < NT) {
        stage32p(Ag + (t + 1) * 32, LATENT, At + (cur ^ 1) * BM * 32, tid);
        stage32p(Bg + (t + 1) * 32, QKVN, Bt + (cur ^ 1) * BN * 32, tid);
      }
      const half_t* Ac = At + cur * BM * 32;
      const half_t* Bc = Bt + cur * BN * 32;
      half8 af[MF], bf[NF];
#pragma unroll
      for (int m = 0; m < MF; ++m) {
        int row = wr + m * 16 + fr;
        af[m] = *(const half8*)(Ac + row * 32 + ((fs ^ ((row >> 1) & 3)) * 8));
      }
#pragma unroll
      for (int n = 0; n < NF; ++n) {
        int row = wc + n * 16 + fr;
        bf[n] = *(const half8*)(Bc + row * 32 + ((fs ^ ((row >> 1) & 3)) * 8));
      }
#pragma unroll
      for (int m = 0; m < MF; ++m)
#pragma unroll
        for (int n = 0; n < NF; ++n)
          acc[m][n] = MFMA(af[m], bf[n], acc[m][n]);
      __syncthreads();
      cur ^= 1;
    }

#pragma unroll
    for (int m = 0; m < MF; ++m)
#pragma unroll
      for (int n = 0; n < NF; ++n)
#pragma unroll
        for (int j = 0; j < 4; ++j) {
          int row = rowBlk + wr + m * 16 + (lane >> 4) * 4 + j;
          int col = colBlk + wc + n * 16 + fr;
          vwT[(size_t)row * N_TOK + col] = (half_t)acc[m][n][j];
        }
  } else {
    const int row = bid - 256;
    float* redm = (float*)smem;
    float* reds = redm + 4;
    const half8* s8 = (const half8*)(S + (size_t)row * N_TOK);

    half8 vv[2];
    float lmax = -1e30f;
#pragma unroll
    for (int i = 0; i < 2; ++i) {
      vv[i] = s8[tid + i * 256];
#pragma unroll
      for (int j = 0; j < 8; ++j) lmax = fmaxf(lmax, (float)vv[i][j]);
    }
#pragma unroll
    for (int off = 32; off; off >>= 1) lmax = fmaxf(lmax, __shfl_xor(lmax, off));
    if ((tid & 63) == 0) redm[tid >> 6] = lmax;
    __syncthreads();
    lmax = fmaxf(fmaxf(redm[0], redm[1]), fmaxf(redm[2], redm[3]));

    float e[16];
    float lsum = 0.f;
#pragma unroll
    for (int i = 0; i < 2; ++i)
#pragma unroll
      for (int j = 0; j < 8; ++j) {
        float ev = __expf((float)vv[i][j] - lmax);
        e[i * 8 + j] = ev;
        lsum += ev;
      }
#pragma unroll
    for (int off = 32; off; off >>= 1) lsum += __shfl_xor(lsum, off);
    if ((tid & 63) == 0) reds[tid >> 6] = lsum;
    __syncthreads();
    float inv = 1.f / (reds[0] + reds[1] + reds[2] + reds[3]);

    half8* p8 = (half8*)(P + (size_t)row * N_TOK);
#pragma unroll
    for (int i = 0; i < 2; ++i) {
      half8 h;
#pragma unroll
      for (int j = 0; j < 8; ++j) h[j] = (half_t)(e[i * 8 + j] * inv);
      p8[tid + i * 256] = h;
    }
  }
}

// ---------------------------------------------------------------------------
// Split-K reduce: out = sum of 4 fp16 partials + bias (f32 out).
// ---------------------------------------------------------------------------
__launch_bounds__(256)
__global__ void reduce_bias4(const half_t* __restrict__ p, const float* __restrict__ bias,
                             float* __restrict__ out) {
  int i = blockIdx.x * 256 + threadIdx.x;  // half8 index
  const size_t stride8 = (size_t)N_TOK * LATENT / 8;
  half8 a = ((const half8*)p)[i];
  half8 b = ((const half8*)p)[i + stride8];
  half8 c = ((const half8*)p)[i + 2 * stride8];
  half8 d = ((const half8*)p)[i + 3 * stride8];
  float4 e0 = ((const float4*)bias)[(i & 127) * 2];
  float4 e1 = ((const float4*)bias)[(i & 127) * 2 + 1];
  float r[8];
#pragma unroll
  for (int j = 0; j < 8; ++j)
    r[j] = (float)a[j] + (float)b[j] + (float)c[j] + (float)d[j];
  float4 o0, o1;
  o0.x = r[0] + e0.x; o0.y = r[1] + e0.y; o0.z = r[2] + e0.z; o0.w = r[3] + e0.w;
  o1.x = r[4] + e1.x; o1.y = r[5] + e1.y; o1.z = r[6] + e1.z; o1.w = r[7] + e1.w;
  ((float4*)out)[i * 2] = o0;
  ((float4*)out)[i * 2 + 1] = o1;
}

// ---------------------------------------------------------------------------
// Preamble (single launch, 8192 blocks): [0,4096) cvt x->fp16 (1M float4s);
// [4096,7168) transpose w_qkv; [7168,8192) transpose w_out.
// ---------------------------------------------------------------------------
DEVI void tr32(const float* __restrict__ in, int ldin,
               half_t* __restrict__ out, int ldout,
               int cb, int rb, int tid, float (*tile)[33]) {
  const int tx = tid & 31;
  const int ty = tid >> 5;
#pragma unroll
  for (int i = ty; i < 32; i += 8)
    tile[i][tx] = in[(size_t)(rb + i) * ldin + cb + tx];
  __syncthreads();
#pragma unroll
  for (int i = ty; i < 32; i += 8)
    out[(size_t)(cb + i) * ldout + rb + tx] = (half_t)tile[tx][i];
}

__launch_bounds__(256)
__global__ void preamble(const float* __restrict__ x, half_t* __restrict__ xb,
                         const float* __restrict__ wq, half_t* __restrict__ wqT,
                         const float* __restrict__ wo, half_t* __restrict__ woT) {
  __shared__ float tile[32][33];
  const int bid = blockIdx.x;
  const int tid = threadIdx.x;
  if (bid < 4096) {
    int i = bid * 256 + tid;  // float4 index, 4096*256 = 1M = all of x
    float4 v = ((const float4*)x)[i];
    half4 h;
    h[0] = (half_t)v.x; h[1] = (half_t)v.y; h[2] = (half_t)v.z; h[3] = (half_t)v.w;
    ((half4*)xb)[i] = h;
  } else if (bid < 7168) {
    int l = bid - 4096;  // 3072 tiles: 96 cols x 32 rows
    tr32(wq, QKVN, wqT, LATENT, (l % 96) * 32, (l / 96) * 32, tid, tile);
  } else {
    int l = bid - 7168;  // 1024 tiles: 32 x 32
    tr32(wo, LATENT, woT, LATENT, (l & 31) * 32, (l >> 5) * 32, tid, tile);
  }
}

extern "C" void kernel_launch(void* const* d_in, const int* in_sizes, int n_in,
                              void* d_out, int out_size, void* d_ws, size_t ws_size,
                              hipStream_t stream) {
  const float* x = (const float*)d_in[0];
  const float* w_qkv = (const float*)d_in[1];
  const float* b_qkv = (const float*)d_in[2];
  const float* w_out = (const float*)d_in[3];
  const float* b_out = (const float*)d_in[4];
  float* out = (float*)d_out;

  char* ws = (char*)d_ws;
  half_t* xb    = (half_t*)(ws);
  half_t* wqkvT = (half_t*)(ws + ((size_t)8 << 20));
  half_t* qkv   = (half_t*)(ws + ((size_t)14 << 20));
  half_t* S     = (half_t*)(ws + ((size_t)46 << 20));
  half_t* P     = (half_t*)(ws + ((size_t)78 << 20));
  half_t* vwT   = (half_t*)(ws + ((size_t)118 << 20));
  half_t* woutT = (half_t*)(ws + ((size_t)126 << 20));
  half_t* parts = (half_t*)(ws + ((size_t)14 << 20));  // qkv+S dead by then

  // 1. preamble: cvt + both transposes in one launch (8192 blocks)
  preamble<<<8192, 256, 0, stream>>>(x, xb, w_qkv, wqkvT, w_out, woutT);
  // 2. qkv = x @ w_qkv + b (q scaled 0.125)  (192 blocks @ 256x256)
  gemm8h<0><<<dim3(QKVN / 256, N_TOK / 256), 512, 0, stream>>>(
      xb, LATENT, wqkvT, LATENT, qkv, QKVN, b_qkv, LATENT);
  // 3. S = q' @ k^T  (256 blocks @ 256x256)
  gemm8h<1><<<dim3(N_TOK / 256, N_TOK / 256), 512, 0, stream>>>(
      qkv, QKVN, qkv + LATENT, QKVN, S, N_TOK, nullptr, LATENT);
  // 4. dual-role: vwT GEMM (256 blocks) + softmax rows (4096 blocks)
  vwt_softmax<<<256 + N_TOK, 256, 0, stream>>>(
      woutT, qkv + 2 * LATENT, vwT, S, P);
  // 5. parts = P @ vwT, split-K=4, fp16 partials  (4 x 64 blocks @ 256x256)
  gemm8h<2><<<dim3(LATENT / 256, N_TOK / 256, 4), 512, 0, stream>>>(
      P, N_TOK, vwT, N_TOK, parts, LATENT, nullptr, 1024);
  // 6. out = sum(parts) + b_out
  reduce_bias4<<<(N_TOK * LATENT) / (256 * 8), 256, 0, stream>>>(parts, b_out, out);
}